// Round 5
// baseline (4833.160 us; speedup 1.0000x reference)
//
#include <hip/hip_runtime.h>
#include <hip/hip_bf16.h>

// MatchLSTM boundary-pointer model on MI355X (gfx950).
// B=32 T=400 J=30 V=50000 D=150 H=150 L=2. Output [B,2,401].
//
// Round 5: rounds 1-4 proved the toolchain pins these kernels at 128 VGPRs
// (launch_bounds / waves_per_eu / LDS-forcing all ignored), so holding
// 150-float weight rows per thread ALWAYS spills. Redesign to FIT 128:
// 1024-thread blocks; recurrent matvec tiled (row-pair x 4 K-splits): 20
// weight quads = 80 VGPRs/thread; match adds a 7-quad Wr overlay (108 total).
// Partial dots combined through LDS. Attention phases re-vectorized (float4),
// pointer-phase D runs on the 124 weight-free threads. All strides padded
// for aligned b128 (Whh->160, pWp/whq->152, giX/P->452, Wr->56/half).

namespace {

constexpr int NBATCH = 32;
constexpr int TLEN   = 400;
constexpr int JQ     = 30;
constexpr int T1     = 401;

__device__ __forceinline__ float sigm(float x){ return 1.f/(1.f+__expf(-x)); }
__device__ __forceinline__ float tanh_f(float x){
  float e = __expf(-2.f*fabsf(x));
  float t = (1.f-e)/(1.f+e);
  return x < 0.f ? -t : t;
}
__device__ __forceinline__ float bf2f(unsigned short u){
  union { unsigned int i; float f; } c; c.i = ((unsigned int)u)<<16; return c.f;
}

#define NW 29
struct WDesc { const void* src[NW]; int off[NW+1]; };

// ---- dtype sniff: bf16-packed words have concentrated bits[14:8].
__global__ void sniff_kernel(const unsigned int* __restrict__ bits, int* __restrict__ flag){
  __shared__ int cnt;
  if (threadIdx.x==0) cnt = 0;
  __syncthreads();
  int hit = 0;
  #pragma unroll
  for (int i=0;i<4;i++){
    unsigned int w = bits[threadIdx.x*4+i];
    unsigned int b = (w>>8)&0x7Fu;
    if (b==0u || (b>=0x38u && b<=0x3Fu)) hit++;
  }
  atomicAdd(&cnt, hit);
  __syncthreads();
  if (threadIdx.x==0) *flag = (cnt > 768) ? 1 : 0;
}

__global__ void convert_weights_kernel(WDesc d, float* __restrict__ out, const int* __restrict__ flag){
  const int isbf = *flag;
  const int total = d.off[NW];
  for (int e = blockIdx.x*blockDim.x+threadIdx.x; e < total; e += gridDim.x*blockDim.x){
    int j = 0;
    while (e >= d.off[j+1]) j++;
    int i = e - d.off[j];
    out[e] = isbf ? bf2f(((const unsigned short*)d.src[j])[i])
                  : ((const float*)d.src[j])[i];
  }
}

// dst[r*ldd+c] = c<cols ? src[r*cols+c] : 0
__global__ void padrows_kernel(const float* __restrict__ src, float* __restrict__ dst,
                               int rows, int cols, int ldd){
  int i = blockIdx.x*blockDim.x+threadIdx.x;
  if (i >= rows*ldd) return;
  int r = i/ldd, c = i-r*ldd;
  dst[i] = (c<cols) ? src[(size_t)r*cols+c] : 0.f;
}

// W3[t*56 + half*28 + ii] = (ii<25)? Wr[(seg*50+half*25+ii)*150 + kw] : 0
//   where seg=t/150, kw=t%150
__global__ void wrt_kernel(const float* __restrict__ Wr, float* __restrict__ W3){
  int i = blockIdx.x*blockDim.x+threadIdx.x;
  if (i >= 450*56) return;
  int t = i/56, r = i-t*56, half = r/28, ii = r-half*28;
  int seg = t/150, kw = t-seg*150;
  W3[i] = (ii<25) ? Wr[(size_t)(seg*50+half*25+ii)*150 + kw] : 0.f;
}

// ---- generic row-tiled projection; out stride ldo (zero-fill K..ldo)
__global__ __launch_bounds__(512) void rowproj_kernel(
    const float* __restrict__ Xrows,
    const int* __restrict__ gather, const void* __restrict__ Etab, const int* __restrict__ bfflag,
    const float* __restrict__ W, const float* __restrict__ bias,
    float* __restrict__ out, int rows, int K, int inner, int mode, int ldw, int offw, int ldo)
{
  __shared__ float xs[8][304];
  const int r0 = blockIdx.x*8;
  int nr = rows - r0; if (nr > 8) nr = 8;
  if (nr <= 0) return;
  const int isbf = gather ? *bfflag : 0;
  for (int e = threadIdx.x; e < nr*inner; e += blockDim.x){
    int r = e/inner, i = e - r*inner;
    float v;
    if (gather){
      size_t base = (size_t)gather[r0+r]*inner + i;
      v = isbf ? bf2f(((const unsigned short*)Etab)[base]) : ((const float*)Etab)[base];
    } else {
      v = Xrows[(size_t)(r0+r)*inner + i];
    }
    xs[r][i] = v;
  }
  __syncthreads();
  for (int k = threadIdx.x; k < ldo; k += blockDim.x){
    if (k < K){
      float b0 = bias ? bias[k] : 0.f;
      float acc[8];
      #pragma unroll
      for (int r=0;r<8;r++) acc[r] = b0;
      if (mode==0){
        for (int i=0;i<inner;i++){
          float wv = W[(size_t)i*ldw + k];
          #pragma unroll
          for (int r=0;r<8;r++) acc[r] += xs[r][i]*wv;
        }
      } else {
        const float* wr = W + (size_t)k*ldw + offw;
        for (int i=0;i<inner;i++){
          float wv = wr[i];
          #pragma unroll
          for (int r=0;r<8;r++) acc[r] += xs[r][i]*wv;
        }
      }
      for (int r=0;r<nr;r++) out[(size_t)(r0+r)*ldo + k] = acc[r];
    } else {
      for (int r=0;r<nr;r++) out[(size_t)(r0+r)*ldo + k] = 0.f;
    }
  }
}

// ---- register macros: 10 quads x 2 rows (Whh) and 7 quads (Wr) -----------
#define Q10(M) M(0) M(1) M(2) M(3) M(4) M(5) M(6) M(7) M(8) M(9)
#define Q7(M)  M(0) M(1) M(2) M(3) M(4) M(5) M(6)

#define DECW(i) float4 wa##i, wb##i;
#define LDW(i)  wa##i = pA4[i]; wb##i = pB4[i];
#define FMA_AB(i) { float4 hv = h4[hq0 + (i)]; \
  aA0 = fmaf(hv.x, wa##i.x, aA0); aA1 = fmaf(hv.y, wa##i.y, aA1); \
  aA0 = fmaf(hv.z, wa##i.z, aA0); aA1 = fmaf(hv.w, wa##i.w, aA1); \
  aB0 = fmaf(hv.x, wb##i.x, aB0); aB1 = fmaf(hv.y, wb##i.y, aB1); \
  aB0 = fmaf(hv.z, wb##i.z, aB0); aB1 = fmaf(hv.w, wb##i.w, aB1); }

#define DECR(i) float4 wr##i;
#define LDR(i)  wr##i = pR4[i];
#define FMA_R(i) { float4 hv = hw4[wq0 + (i)]; \
  c0 = fmaf(hv.x, wr##i.x, c0); c1 = fmaf(hv.y, wr##i.y, c1); \
  c0 = fmaf(hv.z, wr##i.z, c0); c1 = fmaf(hv.w, wr##i.w, c1); }

// ---- merged GRU encoder scan: blocks 0..31 context (S=400), 32..63 query (S=30)
// thread (g=tid%225, s=tid/225) holds rows 2g,2g+1 over K-chunk [40s,40s+40)
__global__ __launch_bounds__(1024,4) void gru_scan_kernel(
    const float* __restrict__ gi0, const float* __restrict__ W0P,
    const float* __restrict__ bh0, float* __restrict__ H0, int S0,
    const float* __restrict__ gi1, const float* __restrict__ W1P,
    const float* __restrict__ bh1, float* __restrict__ H1, int S1)
{
  const int blk = blockIdx.x;
  const float* gi; const float* WP; const float* bh; float* Hs; int S;
  if (blk < 32){ gi = gi0 + (size_t)blk*S0*450;  WP = W0P; bh = bh0;
                 Hs = H0 + (size_t)blk*S0*150;   S = S0; }
  else         { int bb = blk-32;
                 gi = gi1 + (size_t)bb*S1*450;   WP = W1P; bh = bh1;
                 Hs = H1 + (size_t)bb*S1*150;    S = S1; }
  __shared__ __align__(16) float h[160];
  __shared__ float part[1824];     // [4][456]
  const int tid = threadIdx.x;
  const bool wt = tid < 900;
  const int g = wt ? (tid % 225) : 0;
  const int s = wt ? (tid / 225) : 0;
  const int hq0 = s*10;

  Q10(DECW)
  float brA = 0.f, brB = 0.f;
  if (wt){
    const float4* pA4 = (const float4*)(WP + (size_t)(2*g)*160 + s*40);
    const float4* pB4 = pA4 + 40;  // next row (160 floats)
    Q10(LDW)
    if (s==0){ brA = bh[2*g]; brB = bh[2*g+1]; }
  }
  for (int i=tid; i<160; i+=1024) h[i] = 0.f;
  __syncthreads();
  const float4* h4 = (const float4*)h;

  for (int t=0;t<S;t++){
    float g0=0.f,g1=0.f,g2=0.f;
    if (tid < 150){
      const float* gg = gi + (size_t)t*450;
      g0 = gg[tid]; g1 = gg[150+tid]; g2 = gg[300+tid];
    }
    if (wt){
      float aA0=brA, aA1=0.f, aB0=brB, aB1=0.f;
      Q10(FMA_AB)
      float2 pv; pv.x = aA0+aA1; pv.y = aB0+aB1;
      *(float2*)&part[s*456 + 2*g] = pv;
    }
    __syncthreads();
    if (tid < 150){
      float ghr = part[tid]     + part[456+tid]  + part[912+tid]  + part[1368+tid];
      float ghz = part[150+tid] + part[606+tid]  + part[1062+tid] + part[1518+tid];
      float ghn = part[300+tid] + part[756+tid]  + part[1212+tid] + part[1668+tid];
      float r = sigm(g0 + ghr);
      float z = sigm(g1 + ghz);
      float n = tanh_f(g2 + r*ghn);
      float hn = (1.f-z)*n + z*h[tid];
      h[tid] = hn;
      Hs[(size_t)t*150 + tid] = hn;
    }
    __syncthreads();
  }
}

__global__ void zero_hr0_kernel(float* __restrict__ Hr){
  int idx = blockIdx.x*blockDim.x + threadIdx.x;
  if (idx < NBATCH*300){
    int b = idx/300, k = idx - 300*b;
    Hr[(size_t)b*T1*300 + k] = 0.f;
  }
}

// ---- match scan: one block per (batch, dir); 1024 threads.
// tid<900: Whh row-pair/K-split (80 regs) + Wr overlay (28 regs).
// tid>=900: pointer-free helpers (prefetch + attention-apply phase D).
__global__ __launch_bounds__(1024,4) void match_scan_kernel(
    const float* __restrict__ pWp,   // [B,T,152]  Hp@Wp + gate_bias (pad 0)
    const float* __restrict__ whq,   // [B,J,152]  Hq@Wq (pad 0)
    const float* __restrict__ giXf,  // [B,T,452]  Hp@m_Wih_x^T + m_bih (pad 0)
    const float* __restrict__ giXr,
    const float* __restrict__ Pf,    // [B,J,452]  Hq@m_Wih_q^T (pad 0)
    const float* __restrict__ Pr,
    const float* __restrict__ mWhhP, const float* __restrict__ mrWhhP, // [450,160]
    const float* __restrict__ m_bhh, const float* __restrict__ mr_bhh,
    const float* __restrict__ WrT3,  // [450,56]
    const float* __restrict__ wvec,  // [150]
    float* __restrict__ Hr)          // [B,401,300]
{
  const int b   = blockIdx.x;
  const int dir = blockIdx.y;
  const float* giX = dir ? giXr : giXf;
  const float* P   = dir ? Pr   : Pf;
  const float* WP  = dir ? mrWhhP : mWhhP;
  const float* bhh = dir ? mr_bhh : m_bhh;

  __shared__ __align__(16) float Pl[13560];   // [30][452]  54.2 KB
  __shared__ __align__(16) float wqS[4560];   // [30][152]  18.2 KB
  __shared__ __align__(16) float wlS[152];
  __shared__ __align__(16) float pwS[152];
  __shared__ __align__(16) float baseS[152];
  __shared__ __align__(16) float gis[456];
  __shared__ __align__(16) float h[160];
  __shared__ __align__(16) float hw[168];     // [3][2][28] padded h for Wr
  __shared__ float ghs[456];
  __shared__ float part[1824];                // [4][456]
  __shared__ float wrPart[912];               // [2][456]
  __shared__ float sc[32], attw[32];

  const int tid  = threadIdx.x;
  const int lane = tid & 63;
  const int wv   = tid >> 6;
  const int tidD = tid - 900;
  const bool wt  = tid < 900;

  const int g   = wt ? (tid % 225) : 0;
  const int s   = wt ? (tid / 225) : 0;
  const int hq0 = s*10;
  const int rt   = wt ? (tid % 450) : 0;
  const int half = wt ? (tid / 450) : 0;
  const int wq0  = (rt/150)*14 + half*7;

  Q10(DECW)
  Q7(DECR)
  float brA = 0.f, brB = 0.f;
  if (wt){
    const float4* pA4 = (const float4*)(WP + (size_t)(2*g)*160 + s*40);
    const float4* pB4 = pA4 + 40;
    Q10(LDW)
    if (s==0){ brA = bhh[2*g]; brB = bhh[2*g+1]; }
    const float4* pR4 = (const float4*)(WrT3 + (size_t)rt*56 + half*28);
    Q7(LDR)
  }
  for (int e=tid; e<13560; e+=1024) Pl[e]  = P[(size_t)b*13560 + e];
  for (int e=tid; e<4560;  e+=1024) wqS[e] = whq[(size_t)b*4560 + e];
  if (tid < 152) wlS[tid] = (tid<150) ? wvec[tid] : 0.f;
  for (int i=tid; i<160; i+=1024) h[i]  = 0.f;
  for (int i=tid; i<168; i+=1024) hw[i] = 0.f;
  __syncthreads();
  const float4* h4   = (const float4*)h;
  const float4* hw4  = (const float4*)hw;
  const float4* Pl4  = (const float4*)Pl;
  const float4* wqS4 = (const float4*)wqS;
  float4 wl4; wl4.x=wl4.y=wl4.z=wl4.w=0.f;
  if (lane < 38) wl4 = ((const float4*)wlS)[lane];

  for (int t=0;t<TLEN;t++){
    const int tt = dir ? (TLEN-1-t) : t;
    // prefetch (weight-free threads)
    float4 gv4;
    if ((unsigned)tidD < 113u)
      gv4 = *(const float4*)(giX + ((size_t)b*TLEN + tt)*452 + tidD*4);
    if ((unsigned)tidD < 38u){
      float4 pw4 = *(const float4*)(pWp + ((size_t)b*TLEN + tt)*152 + tidD*4);
      *(float4*)&pwS[tidD*4] = pw4;
    }
    // A: partial gh (row-pair x K-split) + partial hWr
    if (wt){
      float aA0=brA, aA1=0.f, aB0=brB, aB1=0.f;
      Q10(FMA_AB)
      float2 pv; pv.x = aA0+aA1; pv.y = aB0+aB1;
      *(float2*)&part[s*456 + 2*g] = pv;
      float c0=0.f, c1=0.f;
      Q7(FMA_R)
      wrPart[half*456 + rt] = c0+c1;
    }
    __syncthreads();                       // b1
    // combine: ghs + baseS(= pw + hWr)
    if (tid < 450){
      ghs[tid] = part[tid] + part[456+tid] + part[912+tid] + part[1368+tid];
    } else if (tid >= 512 && tid < 664){
      int u = tid - 512;
      float v = 0.f;
      if (u < 150){
        v = pwS[u]
          + wrPart[u]     + wrPart[150+u] + wrPart[300+u]
          + wrPart[456+u] + wrPart[606+u] + wrPart[756+u];
      }
      baseS[u] = v;
    }
    __syncthreads();                       // b2
    // B: attention scores, lane<38 x float4 over h, j = wv, wv+16
    {
      float4 b4; b4.x=b4.y=b4.z=b4.w=0.f;
      const bool bl = (lane < 38);
      if (bl) b4 = ((const float4*)baseS)[lane];
      #pragma unroll
      for (int jj=0;jj<2;jj++){
        int j = wv + 16*jj;
        if (j < JQ){
          float acc = 0.f;
          if (bl){
            float4 q4 = wqS4[j*38 + lane];
            acc  = wl4.x * tanh_f(q4.x + b4.x);
            acc = fmaf(wl4.y, tanh_f(q4.y + b4.y), acc);
            acc = fmaf(wl4.z, tanh_f(q4.z + b4.z), acc);
            acc = fmaf(wl4.w, tanh_f(q4.w + b4.w), acc);
          }
          #pragma unroll
          for (int off=32; off; off>>=1) acc += __shfl_down(acc, off);
          if (lane==0) sc[j] = acc;
        }
      }
    }
    __syncthreads();                       // b3
    // C: softmax over J=30 (wave 0)
    if (tid < 64){
      float v = (tid < JQ) ? sc[tid] : -1e30f;
      float m = v;
      #pragma unroll
      for (int off=32; off; off>>=1) m = fmaxf(m, __shfl_down(m, off));
      m = __shfl(m, 0);
      float e = (tid < JQ) ? __expf(v-m) : 0.f;
      float su = e;
      #pragma unroll
      for (int off=32; off; off>>=1) su += __shfl_down(su, off);
      su = __shfl(su, 0);
      if (tid < JQ) attw[tid] = e/su;
    }
    __syncthreads();                       // b4
    // D: gis = giX + attw @ P (weight-free threads, float4)
    if ((unsigned)tidD < 113u){
      float4 acc = gv4;
      #pragma unroll 2
      for (int j=0;j<JQ;j++){
        float a = attw[j];
        float4 p = Pl4[j*113 + tidD];
        acc.x = fmaf(a, p.x, acc.x);
        acc.y = fmaf(a, p.y, acc.y);
        acc.z = fmaf(a, p.z, acc.z);
        acc.w = fmaf(a, p.w, acc.w);
      }
      ((float4*)gis)[tidD] = acc;
    }
    __syncthreads();                       // b5
    // E: GRU combine; update h and padded hw copy; write Hr
    if (tid < 150){
      float r = sigm(gis[tid] + ghs[tid]);
      float z = sigm(gis[150+tid] + ghs[150+tid]);
      float n = tanh_f(gis[300+tid] + r*ghs[300+tid]);
      float hn = (1.f-z)*n + z*h[tid];
      h[tid] = hn;
      int seg = tid/50, rem = tid - seg*50, hf = rem/25, ii = rem - hf*25;
      hw[seg*56 + hf*28 + ii] = hn;
      Hr[((size_t)b*T1 + (t+1))*300 + dir*150 + tid] = hn;
    }
    __syncthreads();                       // b6
  }
}

// ---- pointer decoder (unchanged)
__global__ __launch_bounds__(512,2) void ptr_scan_kernel(
    const float* __restrict__ enc, const float* __restrict__ Hr,
    const float* __restrict__ W2, const float* __restrict__ pv,
    const float* __restrict__ dWih, const float* __restrict__ dWhh,
    const float* __restrict__ dbih, const float* __restrict__ dbhh,
    void* __restrict__ outv, const int* __restrict__ flag)
{
  const int b = blockIdx.x;
  const int tid = threadIdx.x;
  const int isbf = *flag;
  __shared__ float h[300], hW2[300], sl[T1], al[T1], c[300];
  __shared__ float gis[900], ghs[900];
  __shared__ float vl[300];
  __shared__ float red[8];
  if (tid < 300){ h[tid] = 0.f; vl[tid] = pv[tid]; }
  __syncthreads();
  for (int l=0;l<2;l++){
    if (tid < 300){
      float a0=0.f,a1=0.f;
      for (int i=0;i<300;i+=2){
        a0 += h[i]  *W2[(size_t)i*300+tid];
        a1 += h[i+1]*W2[(size_t)(i+1)*300+tid];
      }
      hW2[tid] = a0+a1;
    }
    __syncthreads();
    {
      const int wv = tid>>6, lane = tid&63;
      for (int t=wv; t<T1; t+=8){
        const float* er = enc + ((size_t)b*T1 + t)*300;
        float acc = 0.f;
        for (int k=lane; k<300; k+=64) acc += vl[k]*tanh_f(er[k] + hW2[k]);
        #pragma unroll
        for (int off=32; off; off>>=1) acc += __shfl_down(acc, off);
        if (lane==0) sl[t] = acc;
      }
    }
    __syncthreads();
    {
      float v = (tid < T1) ? sl[tid] : -1e30f;
      float m = v;
      #pragma unroll
      for (int off=32; off; off>>=1) m = fmaxf(m, __shfl_down(m, off));
      if ((tid&63)==0) red[tid>>6] = m;
      __syncthreads();
      float bm = fmaxf(fmaxf(fmaxf(red[0],red[1]),fmaxf(red[2],red[3])),
                       fmaxf(fmaxf(red[4],red[5]),fmaxf(red[6],red[7])));
      float e = (tid < T1) ? __expf(v-bm) : 0.f;
      float su = e;
      #pragma unroll
      for (int off=32; off; off>>=1) su += __shfl_down(su, off);
      __syncthreads();
      if ((tid&63)==0) red[tid>>6] = su;
      __syncthreads();
      float bs = red[0]+red[1]+red[2]+red[3]+red[4]+red[5]+red[6]+red[7];
      if (tid < T1){
        float a = e/bs;
        al[tid] = a;
        size_t oi = ((size_t)b*2 + l)*T1 + tid;
        if (isbf) ((__hip_bfloat16*)outv)[oi] = __float2bfloat16(a);
        else      ((float*)outv)[oi] = a;
      }
    }
    __syncthreads();
    if (tid < 300){
      float acc = 0.f;
      for (int t=0;t<T1;t++) acc += al[t]*Hr[((size_t)b*T1 + t)*300 + tid];
      c[tid] = acc;
    }
    __syncthreads();
    for (int k=tid; k<900; k+=blockDim.x){
      const float* wi = dWih + (size_t)k*300;
      const float* wh = dWhh + (size_t)k*300;
      float a0 = dbih[k], a1 = dbhh[k];
      for (int i=0;i<300;i++){ a0 += c[i]*wi[i]; a1 += h[i]*wh[i]; }
      gis[k] = a0; ghs[k] = a1;
    }
    __syncthreads();
    if (tid < 300){
      float r = sigm(gis[tid] + ghs[tid]);
      float z = sigm(gis[300+tid] + ghs[300+tid]);
      float n = tanh_f(gis[600+tid] + r*ghs[600+tid]);
      h[tid] = (1.f-z)*n + z*h[tid];
    }
    __syncthreads();
  }
}

} // namespace

extern "C" void kernel_launch(void* const* d_in, const int* in_sizes, int n_in,
                              void* d_out, int out_size, void* d_ws, size_t ws_size,
                              hipStream_t stream)
{
  (void)in_sizes; (void)n_in; (void)out_size; (void)ws_size;
  float* ws = (float*)d_ws;
  int* flag = (int*)d_ws;

  static const int wsz[NW] = {
    67500,67500,450,450,
    67500,67500,450,450,
    22500,22500,22500,150,150,1,
    135000,67500,450,450,
    135000,67500,450,450,
    90000,90000,300,
    270000,270000,900,900
  };
  WDesc desc;
  int cum = 0;
  for (int j=0;j<NW;j++){ desc.src[j] = d_in[3+j]; desc.off[j] = cum; cum += wsz[j]; }
  desc.off[NW] = cum;

  float* WB = ws + 16;
  const float* P_ctx_Wih = WB + desc.off[0];
  const float* P_ctx_Whh = WB + desc.off[1];
  const float* P_ctx_bih = WB + desc.off[2];
  const float* P_ctx_bhh = WB + desc.off[3];
  const float* P_q_Wih   = WB + desc.off[4];
  const float* P_q_Whh   = WB + desc.off[5];
  const float* P_q_bih   = WB + desc.off[6];
  const float* P_q_bhh   = WB + desc.off[7];
  const float* P_Wq      = WB + desc.off[8];
  const float* P_Wp      = WB + desc.off[9];
  const float* P_Wr      = WB + desc.off[10];
  const float* P_w       = WB + desc.off[11];
  const float* P_gb      = WB + desc.off[12];
  const float* P_m_Wih   = WB + desc.off[14];
  const float* P_m_Whh   = WB + desc.off[15];
  const float* P_m_bih   = WB + desc.off[16];
  const float* P_m_bhh   = WB + desc.off[17];
  const float* P_mr_Wih  = WB + desc.off[18];
  const float* P_mr_Whh  = WB + desc.off[19];
  const float* P_mr_bih  = WB + desc.off[20];
  const float* P_mr_bhh  = WB + desc.off[21];
  const float* P_W1      = WB + desc.off[22];
  const float* P_W2      = WB + desc.off[23];
  const float* P_pv      = WB + desc.off[24];
  const float* P_dWih    = WB + desc.off[25];
  const float* P_dWhh    = WB + desc.off[26];
  const float* P_dbih    = WB + desc.off[27];
  const float* P_dbhh    = WB + desc.off[28];

  size_t p = 16 + 1468512;
  float* ctxWhhP = ws + p; p += 72000;    // [450,160]
  float* qWhhP   = ws + p; p += 72000;
  float* mWhhP   = ws + p; p += 72000;
  float* mrWhhP  = ws + p; p += 72000;
  float* WrT3    = ws + p; p += 25200;    // [450,56]

  float* ctx_gi = ws + p; p += 5760000;   // [B,T,450]; reused as enc later
  float* q_gi   = ws + p; p += 432000;    // [B,J,450]
  float* HpB    = ws + p; p += 1920000;   // [B,T,150]
  float* HqB    = ws + p; p += 144000;    // [B,J,150]
  float* whqB   = ws + p; p += 145920;    // [B,J,152]
  float* PfB    = ws + p; p += 433920;    // [B,J,452]
  float* PrB    = ws + p; p += 433920;
  float* pWpB   = ws + p; p += 1945600;   // [B,T,152]
  float* giXfB  = ws + p; p += 5785600;   // [B,T,452]
  float* giXrB  = ws + p; p += 5785600;
  float* HrB    = ws + p; p += 3849600;   // [B,401,300]
  float* encB   = ctx_gi;                 // [B,401,300]

  // 1) dtype sniff + weight conversion + padded layouts
  sniff_kernel<<<1,256,0,stream>>>((const unsigned int*)d_in[2], flag);
  convert_weights_kernel<<<512,256,0,stream>>>(desc, WB, flag);
  padrows_kernel<<<(450*160+255)/256,256,0,stream>>>(P_ctx_Whh, ctxWhhP, 450,150,160);
  padrows_kernel<<<(450*160+255)/256,256,0,stream>>>(P_q_Whh,   qWhhP,   450,150,160);
  padrows_kernel<<<(450*160+255)/256,256,0,stream>>>(P_m_Whh,   mWhhP,   450,150,160);
  padrows_kernel<<<(450*160+255)/256,256,0,stream>>>(P_mr_Whh,  mrWhhP,  450,150,160);
  wrt_kernel<<<(450*56+255)/256,256,0,stream>>>(P_Wr, WrT3);

  // 2) embedding + input projections for both encoders
  rowproj_kernel<<<1600,512,0,stream>>>(nullptr,(const int*)d_in[0], d_in[2], flag,
                                        P_ctx_Wih, P_ctx_bih, ctx_gi, 12800,450,150,1,150,0,450);
  rowproj_kernel<<<120,512,0,stream>>>(nullptr,(const int*)d_in[1], d_in[2], flag,
                                       P_q_Wih, P_q_bih, q_gi, 960,450,150,1,150,0,450);

  // 3) encoder scans
  gru_scan_kernel<<<64,1024,0,stream>>>(ctx_gi, ctxWhhP, P_ctx_bhh, HpB, 400,
                                        q_gi,   qWhhP,   P_q_bhh,   HqB, 30);

  // 4) Hq/Hp-dependent precomputations (padded strides)
  rowproj_kernel<<<120,192,0,stream>>>(HqB,nullptr,nullptr,nullptr, P_Wq, nullptr,
                                       whqB, 960,150,150,0,150,0,152);
  rowproj_kernel<<<120,512,0,stream>>>(HqB,nullptr,nullptr,nullptr, P_m_Wih, nullptr,
                                       PfB, 960,450,150,1,300,150,452);
  rowproj_kernel<<<120,512,0,stream>>>(HqB,nullptr,nullptr,nullptr, P_mr_Wih, nullptr,
                                       PrB, 960,450,150,1,300,150,452);
  rowproj_kernel<<<1600,192,0,stream>>>(HpB,nullptr,nullptr,nullptr, P_Wp, P_gb,
                                        pWpB, 12800,150,150,0,150,0,152);
  rowproj_kernel<<<1600,512,0,stream>>>(HpB,nullptr,nullptr,nullptr, P_m_Wih, P_m_bih,
                                        giXfB, 12800,450,150,1,300,0,452);
  rowproj_kernel<<<1600,512,0,stream>>>(HpB,nullptr,nullptr,nullptr, P_mr_Wih, P_mr_bih,
                                        giXrB, 12800,450,150,1,300,0,452);

  // 5) match scans (fwd+bwd concurrent)
  zero_hr0_kernel<<<(NBATCH*300+511)/512,512,0,stream>>>(HrB);
  match_scan_kernel<<<dim3(NBATCH,2),1024,0,stream>>>(pWpB, whqB, giXfB, giXrB,
                                                      PfB, PrB, mWhhP, mrWhhP,
                                                      P_m_bhh, P_mr_bhh, WrT3, P_w, HrB);

  // 6) pointer decoder
  rowproj_kernel<<<1604,320,0,stream>>>(HrB,nullptr,nullptr,nullptr, P_W1, nullptr,
                                        encB, 12832,300,300,0,300,0,300);
  ptr_scan_kernel<<<32,512,0,stream>>>(encB, HrB, P_W2, P_pv,
                                       P_dWih, P_dWhh, P_dbih, P_dbhh, d_out, flag);
}

// Round 6
// 3643.293 us; speedup vs baseline: 1.3266x; 1.3266x over previous
//
#include <hip/hip_runtime.h>
#include <hip/hip_bf16.h>

// MatchLSTM boundary-pointer model on MI355X (gfx950).
// B=32 T=400 J=30 V=50000 D=150 H=150 L=2. Output [B,2,401].
//
// Round 6. Empirical law from rounds 1-5: VGPR budget = 65536/blockSize
// (512thr->128, 1024thr->64), immune to launch_bounds/waves_per_eu/LDS
// forcing. So per-block register capacity = 65536 floats, and the match
// weight set (Whh 450x150 + Wr^T 150x150 = 360KB) can never be fully
// register-resident. Design to the law:
//   512 threads; W = [Whh; WrT] 600 rows x 152(pad).
//   - rows 0..511: first 104 floats in 26 float4 REGS/thread (+~20 temps
//     = ~124 <= 128, no spill), last 46 floats in LDS s2W stored TRANSPOSED
//     [quad][row] (unit lane stride -> conflict-free).
//   - rows 512..599 in LDS extW (transposed), 88 rows x 5 K-groups on
//     threads<440, partials summed in combine.
//   - P / whq stream from L2 (step-invariant, shared, coalesced f4 reads).
// LDS total 163,776 B <= 160 KiB. GRU encoders same scheme (450 rows, no
// streaming). All per-step LDS weight reads conflict-free.

namespace {

constexpr int NBATCH = 32;
constexpr int TLEN   = 400;
constexpr int JQ     = 30;
constexpr int T1     = 401;

__device__ __forceinline__ float sigm(float x){ return 1.f/(1.f+__expf(-x)); }
__device__ __forceinline__ float tanh_f(float x){
  float e = __expf(-2.f*fabsf(x));
  float t = (1.f-e)/(1.f+e);
  return x < 0.f ? -t : t;
}
__device__ __forceinline__ float bf2f(unsigned short u){
  union { unsigned int i; float f; } c; c.i = ((unsigned int)u)<<16; return c.f;
}

#define NW 29
struct WDesc { const void* src[NW]; int off[NW+1]; };

__global__ void sniff_kernel(const unsigned int* __restrict__ bits, int* __restrict__ flag){
  __shared__ int cnt;
  if (threadIdx.x==0) cnt = 0;
  __syncthreads();
  int hit = 0;
  #pragma unroll
  for (int i=0;i<4;i++){
    unsigned int w = bits[threadIdx.x*4+i];
    unsigned int b = (w>>8)&0x7Fu;
    if (b==0u || (b>=0x38u && b<=0x3Fu)) hit++;
  }
  atomicAdd(&cnt, hit);
  __syncthreads();
  if (threadIdx.x==0) *flag = (cnt > 768) ? 1 : 0;
}

__global__ void convert_weights_kernel(WDesc d, float* __restrict__ out, const int* __restrict__ flag){
  const int isbf = *flag;
  const int total = d.off[NW];
  for (int e = blockIdx.x*blockDim.x+threadIdx.x; e < total; e += gridDim.x*blockDim.x){
    int j = 0;
    while (e >= d.off[j+1]) j++;
    int i = e - d.off[j];
    out[e] = isbf ? bf2f(((const unsigned short*)d.src[j])[i])
                  : ((const float*)d.src[j])[i];
  }
}

// dst[r*ldd+c] = c<cols ? src[r*cols+c] : 0
__global__ void padrows_kernel(const float* __restrict__ src, float* __restrict__ dst,
                               int rows, int cols, int ldd){
  int i = blockIdx.x*blockDim.x+threadIdx.x;
  if (i >= rows*ldd) return;
  int r = i/ldd, c = i-r*ldd;
  dst[i] = (c<cols) ? src[(size_t)r*cols+c] : 0.f;
}

// Wcat[600][152]: rows<450 = Whh; rows>=450: Wcat[450+k][i] = Wr[i][k]
__global__ void build_wcat_kernel(const float* __restrict__ Whh, const float* __restrict__ Wr,
                                  float* __restrict__ Wcat){
  int i = blockIdx.x*blockDim.x+threadIdx.x;
  if (i >= 600*152) return;
  int r = i/152, c = i-r*152;
  float v = 0.f;
  if (c < 150){
    if (r < 450) v = Whh[(size_t)r*150+c];
    else         v = Wr[(size_t)c*150 + (r-450)];
  }
  Wcat[i] = v;
}

// s2q[(q*512+r)*4+p] = Wcat[r*152+104+4q+p]  (q<12, r<512)
// ext[(q*88+i)*4+p]  = Wcat[(512+i)*152+4q+p] (q<38, i<88)
__global__ void build_msplit_kernel(const float* __restrict__ Wcat,
                                    float* __restrict__ s2q, float* __restrict__ ext){
  int i = blockIdx.x*blockDim.x+threadIdx.x;
  if (i < 24576){
    int q = i/2048, rem = i-q*2048, r = rem/4, p = rem-r*4;
    s2q[i] = Wcat[(size_t)r*152 + 104 + 4*q + p];
  } else if (i < 24576+13376){
    int k = i-24576;
    int q = k/352, rem = k-q*352, ii = rem/4, p = rem-ii*4;
    ext[k] = Wcat[(size_t)(512+ii)*152 + 4*q + p];
  }
}

// s2q[(q*452+r)*4+p] = (r<450) ? Wpad[r*152+104+4q+p] : 0   (q<12, r<452)
__global__ void build_gsplit_kernel(const float* __restrict__ Wpad, float* __restrict__ s2q){
  int i = blockIdx.x*blockDim.x+threadIdx.x;
  if (i >= 12*452*4) return;
  int q = i/1808, rem = i-q*1808, r = rem/4, p = rem-r*4;
  s2q[i] = (r<450) ? Wpad[(size_t)r*152 + 104 + 4*q + p] : 0.f;
}

// ---- generic row-tiled projection; out stride ldo (zero-fill K..ldo)
__global__ __launch_bounds__(512) void rowproj_kernel(
    const float* __restrict__ Xrows,
    const int* __restrict__ gather, const void* __restrict__ Etab, const int* __restrict__ bfflag,
    const float* __restrict__ W, const float* __restrict__ bias,
    float* __restrict__ out, int rows, int K, int inner, int mode, int ldw, int offw, int ldo)
{
  __shared__ float xs[8][304];
  const int r0 = blockIdx.x*8;
  int nr = rows - r0; if (nr > 8) nr = 8;
  if (nr <= 0) return;
  const int isbf = gather ? *bfflag : 0;
  for (int e = threadIdx.x; e < nr*inner; e += blockDim.x){
    int r = e/inner, i = e - r*inner;
    float v;
    if (gather){
      size_t base = (size_t)gather[r0+r]*inner + i;
      v = isbf ? bf2f(((const unsigned short*)Etab)[base]) : ((const float*)Etab)[base];
    } else {
      v = Xrows[(size_t)(r0+r)*inner + i];
    }
    xs[r][i] = v;
  }
  __syncthreads();
  for (int k = threadIdx.x; k < ldo; k += blockDim.x){
    if (k < K){
      float b0 = bias ? bias[k] : 0.f;
      float acc[8];
      #pragma unroll
      for (int r=0;r<8;r++) acc[r] = b0;
      if (mode==0){
        for (int i=0;i<inner;i++){
          float wv = W[(size_t)i*ldw + k];
          #pragma unroll
          for (int r=0;r<8;r++) acc[r] += xs[r][i]*wv;
        }
      } else {
        const float* wr = W + (size_t)k*ldw + offw;
        for (int i=0;i<inner;i++){
          float wv = wr[i];
          #pragma unroll
          for (int r=0;r<8;r++) acc[r] += xs[r][i]*wv;
        }
      }
      for (int r=0;r<nr;r++) out[(size_t)(r0+r)*ldo + k] = acc[r];
    } else {
      for (int r=0;r<nr;r++) out[(size_t)(r0+r)*ldo + k] = 0.f;
    }
  }
}

// ---- 26-quad register macros ---------------------------------------------
#define R26(M) M(0) M(1) M(2) M(3) M(4) M(5) M(6) M(7) M(8) M(9) M(10) M(11) \
               M(12) M(13) M(14) M(15) M(16) M(17) M(18) M(19) M(20) M(21) \
               M(22) M(23) M(24) M(25)
#define DECW(i) float4 w##i;
#define LDW(i)  w##i = wrow4[i];
#define FMAW(i) { float4 hq = h4[i]; \
  acc0 = fmaf(hq.x, w##i.x, acc0); acc1 = fmaf(hq.y, w##i.y, acc1); \
  acc0 = fmaf(hq.z, w##i.z, acc0); acc1 = fmaf(hq.w, w##i.w, acc1); }

// ---- merged GRU encoder scan: blocks 0..31 context (S=400), 32..63 query (S=30)
__global__ __launch_bounds__(512) void gru_scan_kernel(
    const float* __restrict__ gi0, const float* __restrict__ Wp0,
    const float* __restrict__ s2q0, const float* __restrict__ bh0,
    float* __restrict__ H0, int S0,
    const float* __restrict__ gi1, const float* __restrict__ Wp1,
    const float* __restrict__ s2q1, const float* __restrict__ bh1,
    float* __restrict__ H1, int S1)
{
  const int blk = blockIdx.x;
  const float* gi; const float* Wpad; const float* s2qG; const float* bh; float* Hs; int S;
  if (blk < 32){ gi = gi0 + (size_t)blk*S0*450;  Wpad = Wp0; s2qG = s2q0; bh = bh0;
                 Hs = H0 + (size_t)blk*S0*150;   S = S0; }
  else         { int bb = blk-32;
                 gi = gi1 + (size_t)bb*S1*450;   Wpad = Wp1; s2qG = s2q1; bh = bh1;
                 Hs = H1 + (size_t)bb*S1*150;    S = S1; }
  __shared__ float4 s2W[12*452];              // transposed [q][r], 86,784 B
  __shared__ __align__(16) float h[152];
  __shared__ float gh[452];
  const int tid = threadIdx.x;

  R26(DECW)
  float br = 0.f;
  {
    const float4* wrow4 = (const float4*)(Wpad + (size_t)((tid<450)?tid:0)*152);
    R26(LDW)
    if (tid<450) br = bh[tid];
  }
  for (int e=tid; e<12*452; e+=512) s2W[e] = ((const float4*)s2qG)[e];
  if (tid < 152) h[tid] = 0.f;
  __syncthreads();
  const float4* h4 = (const float4*)h;

  for (int t=0;t<S;t++){
    float g0=0.f,g1=0.f,g2=0.f;
    if (tid < 150){
      const float* gg = gi + (size_t)t*450;
      g0 = gg[tid]; g1 = gg[150+tid]; g2 = gg[300+tid];
    }
    if (tid < 450){
      float acc0=br, acc1=0.f;
      R26(FMAW)
      #pragma unroll
      for (int q=0;q<12;q++){
        float4 wq = s2W[q*452+tid]; float4 hq = h4[26+q];
        acc0 = fmaf(hq.x, wq.x, acc0); acc1 = fmaf(hq.y, wq.y, acc1);
        acc0 = fmaf(hq.z, wq.z, acc0); acc1 = fmaf(hq.w, wq.w, acc1);
      }
      gh[tid] = acc0+acc1;
    }
    __syncthreads();
    if (tid < 150){
      float r = sigm(g0 + gh[tid]);
      float z = sigm(g1 + gh[150+tid]);
      float n = tanh_f(g2 + r*gh[300+tid]);
      float hn = (1.f-z)*n + z*h[tid];
      h[tid] = hn;
      Hs[(size_t)t*150 + tid] = hn;
    }
    __syncthreads();
  }
}

__global__ void zero_hr0_kernel(float* __restrict__ Hr){
  int idx = blockIdx.x*blockDim.x + threadIdx.x;
  if (idx < NBATCH*300){
    int b = idx/300, k = idx - 300*b;
    Hr[(size_t)b*T1*300 + k] = 0.f;
  }
}

// ---- match scan: one block per (batch, dir); 512 threads, 128-reg law.
__global__ __launch_bounds__(512) void match_scan_kernel(
    const float* __restrict__ pWp,   // [B,T,152]
    const float* __restrict__ whq,   // [B,J,152]
    const float* __restrict__ giXf,  // [B,T,452]
    const float* __restrict__ giXr,
    const float* __restrict__ Pf,    // [B,J,452]
    const float* __restrict__ Pr,
    const float* __restrict__ WcatF, const float* __restrict__ WcatR, // [600][152]
    const float* __restrict__ s2qF,  const float* __restrict__ s2qR,  // [12][512] f4
    const float* __restrict__ extF,  const float* __restrict__ extR,  // [38][88] f4
    const float* __restrict__ m_bhh, const float* __restrict__ mr_bhh,
    const float* __restrict__ wvec,  // [150]
    float* __restrict__ Hr)          // [B,401,300]
{
  const int b   = blockIdx.x;
  const int dir = blockIdx.y;
  const float* giX  = dir ? giXr : giXf;
  const float* P    = dir ? Pr   : Pf;
  const float* Wcat = dir ? WcatR : WcatF;
  const float* s2qG = dir ? s2qR  : s2qF;
  const float* extG = dir ? extR  : extF;
  const float* bhh  = dir ? mr_bhh : m_bhh;

  __shared__ float4 s2W[12*512];              // 98,304 B  (transposed [q][r])
  __shared__ float4 extW[38*88];              // 53,504 B  (transposed [q][i])
  __shared__ float4 uS[339];                  //  5,424 B  (partS [5][96] / dpart [3][113])
  __shared__ __align__(16) float h[152];      //    608
  __shared__ float ghsRaw[512];               //  2,048
  __shared__ __align__(16) float base[152];   //    608
  __shared__ __align__(16) float gis[452];    //  1,808
  __shared__ __align__(16) float pwS[152];    //    608
  __shared__ __align__(16) float wlS[152];    //    608
  __shared__ float sc[32], attw[32];          //    256   -> total 163,776 B

  const int tid  = threadIdx.x;
  const int lane = tid & 63;
  const int wv   = tid >> 6;
  const int er   = (tid < 440) ? (tid % 88) : 0;   // ext row index
  const int kg   = (tid < 440) ? (tid / 88) : 0;   // ext K-group
  const int dq   = (tid < 339) ? (tid % 113) : 0;  // D-phase quad
  const int djg  = (tid < 339) ? (tid / 113) : 0;  // D-phase j-group

  R26(DECW)
  float br;
  {
    const float4* wrow4 = (const float4*)(Wcat + (size_t)tid*152);
    R26(LDW)
    br = (tid < 450) ? bhh[tid] : 0.f;
  }
  for (int e=tid; e<12*512; e+=512) s2W[e]  = ((const float4*)s2qG)[e];
  for (int e=tid; e<38*88;  e+=512) extW[e] = ((const float4*)extG)[e];
  if (tid < 152){
    h[tid] = 0.f;
    base[tid] = 0.f;
    wlS[tid] = (tid<150) ? wvec[tid] : 0.f;
  }
  __syncthreads();
  const float4* h4 = (const float4*)h;

  for (int t=0;t<TLEN;t++){
    const int tt = dir ? (TLEN-1-t) : t;

    // A: full row dot for rows 0..511 (26 reg quads + 12 LDS quads);
    //    ext rows 512..599 partials; pw prefetch.
    {
      float acc0=br, acc1=0.f;
      R26(FMAW)
      #pragma unroll
      for (int q=0;q<12;q++){
        float4 wq = s2W[q*512+tid]; float4 hq = h4[26+q];
        acc0 = fmaf(hq.x, wq.x, acc0); acc1 = fmaf(hq.y, wq.y, acc1);
        acc0 = fmaf(hq.z, wq.z, acc0); acc1 = fmaf(hq.w, wq.w, acc1);
      }
      ghsRaw[tid] = acc0+acc1;
    }
    if (tid < 440){
      float e0=0.f, e1=0.f;
      #pragma unroll
      for (int j=0;j<8;j++){
        int q = kg*8+j;
        if (q < 38){
          float4 wq = extW[q*88+er]; float4 hq = h4[q];
          e0 = fmaf(hq.x, wq.x, e0); e1 = fmaf(hq.y, wq.y, e1);
          e0 = fmaf(hq.z, wq.z, e0); e1 = fmaf(hq.w, wq.w, e1);
        }
      }
      ((float*)uS)[kg*96+er] = e0+e1;
    } else if (tid < 478){
      int u = tid-440;
      ((float4*)pwS)[u] = ((const float4*)(pWp + ((size_t)b*TLEN + tt)*152))[u];
    }
    __syncthreads();                       // b1

    // combine: base[k] = pw[k] + (h@Wr)[k]
    if (tid < 150){
      float v = pwS[tid];
      if (tid < 62) v += ghsRaw[450+tid];
      else {
        int k = tid-62;
        const float* pS = (const float*)uS;
        v += pS[k] + pS[96+k] + pS[192+k] + pS[288+k] + pS[384+k];
      }
      base[tid] = v;
    }
    __syncthreads();                       // b2

    // B: s[j] = sum_k w[k] tanh(whq[j,k] + base[k]); whq streamed from L2
    #pragma unroll
    for (int jj=0;jj<4;jj++){
      int j = wv + 8*jj;
      float a = 0.f;
      if (j < JQ && lane < 38){
        float4 q4 = ((const float4*)(whq + ((size_t)b*JQ + j)*152))[lane];
        float4 b4 = ((const float4*)base)[lane];
        float4 w4 = ((const float4*)wlS)[lane];
        a = w4.x*tanh_f(q4.x+b4.x);
        a = fmaf(w4.y, tanh_f(q4.y+b4.y), a);
        a = fmaf(w4.z, tanh_f(q4.z+b4.z), a);
        a = fmaf(w4.w, tanh_f(q4.w+b4.w), a);
      }
      #pragma unroll
      for (int off=32; off; off>>=1) a += __shfl_down(a, off);
      if (j < JQ && lane==0) sc[j] = a;
    }
    __syncthreads();                       // b3

    // C: softmax over J=30 (wave 0)
    if (tid < 64){
      float v = (tid < JQ) ? sc[tid] : -1e30f;
      float m = v;
      #pragma unroll
      for (int off=32; off; off>>=1) m = fmaxf(m, __shfl_down(m, off));
      m = __shfl(m, 0);
      float e = (tid < JQ) ? __expf(v-m) : 0.f;
      float su = e;
      #pragma unroll
      for (int off=32; off; off>>=1) su += __shfl_down(su, off);
      su = __shfl(su, 0);
      if (tid < JQ) attw[tid] = e/su;
    }
    __syncthreads();                       // b4

    // D1: partial attw @ P (P streamed from L2, coalesced f4)
    if (tid < 339){
      const float4* P4 = (const float4*)(P + ((size_t)b*JQ + djg*10)*452) + dq;
      float4 a; a.x=0.f; a.y=0.f; a.z=0.f; a.w=0.f;
      #pragma unroll 2
      for (int j=0;j<10;j++){
        float aw = attw[djg*10+j];
        float4 p = P4[(size_t)j*113];
        a.x = fmaf(aw, p.x, a.x); a.y = fmaf(aw, p.y, a.y);
        a.z = fmaf(aw, p.z, a.z); a.w = fmaf(aw, p.w, a.w);
      }
      uS[djg*113+dq] = a;
    }
    __syncthreads();                       // b5

    // D2: gis = giX + sum of 3 partials
    if (tid < 113){
      float4 gq = ((const float4*)(giX + ((size_t)b*TLEN + tt)*452))[tid];
      float4 d0 = uS[tid], d1 = uS[113+tid], d2 = uS[226+tid];
      gq.x += d0.x+d1.x+d2.x; gq.y += d0.y+d1.y+d2.y;
      gq.z += d0.z+d1.z+d2.z; gq.w += d0.w+d1.w+d2.w;
      ((float4*)gis)[tid] = gq;
    }
    __syncthreads();                       // b6

    // E: GRU combine, write Hr
    if (tid < 150){
      float r = sigm(gis[tid] + ghsRaw[tid]);
      float z = sigm(gis[150+tid] + ghsRaw[150+tid]);
      float n = tanh_f(gis[300+tid] + r*ghsRaw[300+tid]);
      float hn = (1.f-z)*n + z*h[tid];
      h[tid] = hn;
      Hr[((size_t)b*T1 + (t+1))*300 + dir*150 + tid] = hn;
    }
    __syncthreads();                       // b7
  }
}

// ---- pointer decoder
__global__ __launch_bounds__(512,2) void ptr_scan_kernel(
    const float* __restrict__ enc, const float* __restrict__ Hr,
    const float* __restrict__ W2, const float* __restrict__ pv,
    const float* __restrict__ dWih, const float* __restrict__ dWhh,
    const float* __restrict__ dbih, const float* __restrict__ dbhh,
    void* __restrict__ outv, const int* __restrict__ flag)
{
  const int b = blockIdx.x;
  const int tid = threadIdx.x;
  const int isbf = *flag;
  __shared__ float h[300], hW2[300], sl[T1], al[T1], c[300];
  __shared__ float gis[900], ghs[900];
  __shared__ float vl[300];
  __shared__ float red[8];
  if (tid < 300){ h[tid] = 0.f; vl[tid] = pv[tid]; }
  __syncthreads();
  for (int l=0;l<2;l++){
    if (tid < 300){
      float a0=0.f,a1=0.f;
      for (int i=0;i<300;i+=2){
        a0 += h[i]  *W2[(size_t)i*300+tid];
        a1 += h[i+1]*W2[(size_t)(i+1)*300+tid];
      }
      hW2[tid] = a0+a1;
    }
    __syncthreads();
    {
      const int wv = tid>>6, lane = tid&63;
      for (int t=wv; t<T1; t+=8){
        const float* er = enc + ((size_t)b*T1 + t)*300;
        float acc = 0.f;
        for (int k=lane; k<300; k+=64) acc += vl[k]*tanh_f(er[k] + hW2[k]);
        #pragma unroll
        for (int off=32; off; off>>=1) acc += __shfl_down(acc, off);
        if (lane==0) sl[t] = acc;
      }
    }
    __syncthreads();
    {
      float v = (tid < T1) ? sl[tid] : -1e30f;
      float m = v;
      #pragma unroll
      for (int off=32; off; off>>=1) m = fmaxf(m, __shfl_down(m, off));
      if ((tid&63)==0) red[tid>>6] = m;
      __syncthreads();
      float bm = fmaxf(fmaxf(fmaxf(red[0],red[1]),fmaxf(red[2],red[3])),
                       fmaxf(fmaxf(red[4],red[5]),fmaxf(red[6],red[7])));
      float e = (tid < T1) ? __expf(v-bm) : 0.f;
      float su = e;
      #pragma unroll
      for (int off=32; off; off>>=1) su += __shfl_down(su, off);
      __syncthreads();
      if ((tid&63)==0) red[tid>>6] = su;
      __syncthreads();
      float bs = red[0]+red[1]+red[2]+red[3]+red[4]+red[5]+red[6]+red[7];
      if (tid < T1){
        float a = e/bs;
        al[tid] = a;
        size_t oi = ((size_t)b*2 + l)*T1 + tid;
        if (isbf) ((__hip_bfloat16*)outv)[oi] = __float2bfloat16(a);
        else      ((float*)outv)[oi] = a;
      }
    }
    __syncthreads();
    if (tid < 300){
      float acc = 0.f;
      for (int t=0;t<T1;t++) acc += al[t]*Hr[((size_t)b*T1 + t)*300 + tid];
      c[tid] = acc;
    }
    __syncthreads();
    for (int k=tid; k<900; k+=blockDim.x){
      const float* wi = dWih + (size_t)k*300;
      const float* wh = dWhh + (size_t)k*300;
      float a0 = dbih[k], a1 = dbhh[k];
      for (int i=0;i<300;i++){ a0 += c[i]*wi[i]; a1 += h[i]*wh[i]; }
      gis[k] = a0; ghs[k] = a1;
    }
    __syncthreads();
    if (tid < 300){
      float r = sigm(gis[tid] + ghs[tid]);
      float z = sigm(gis[300+tid] + ghs[300+tid]);
      float n = tanh_f(gis[600+tid] + r*ghs[600+tid]);
      h[tid] = (1.f-z)*n + z*h[tid];
    }
    __syncthreads();
  }
}

} // namespace

extern "C" void kernel_launch(void* const* d_in, const int* in_sizes, int n_in,
                              void* d_out, int out_size, void* d_ws, size_t ws_size,
                              hipStream_t stream)
{
  (void)in_sizes; (void)n_in; (void)out_size; (void)ws_size;
  float* ws = (float*)d_ws;
  int* flag = (int*)d_ws;

  static const int wsz[NW] = {
    67500,67500,450,450,
    67500,67500,450,450,
    22500,22500,22500,150,150,1,
    135000,67500,450,450,
    135000,67500,450,450,
    90000,90000,300,
    270000,270000,900,900
  };
  WDesc desc;
  int cum = 0;
  for (int j=0;j<NW;j++){ desc.src[j] = d_in[3+j]; desc.off[j] = cum; cum += wsz[j]; }
  desc.off[NW] = cum;

  float* WB = ws + 16;
  const float* P_ctx_Wih = WB + desc.off[0];
  const float* P_ctx_Whh = WB + desc.off[1];
  const float* P_ctx_bih = WB + desc.off[2];
  const float* P_ctx_bhh = WB + desc.off[3];
  const float* P_q_Wih   = WB + desc.off[4];
  const float* P_q_Whh   = WB + desc.off[5];
  const float* P_q_bih   = WB + desc.off[6];
  const float* P_q_bhh   = WB + desc.off[7];
  const float* P_Wq      = WB + desc.off[8];
  const float* P_Wp      = WB + desc.off[9];
  const float* P_Wr      = WB + desc.off[10];
  const float* P_w       = WB + desc.off[11];
  const float* P_gb      = WB + desc.off[12];
  const float* P_m_Wih   = WB + desc.off[14];
  const float* P_m_Whh   = WB + desc.off[15];
  const float* P_m_bih   = WB + desc.off[16];
  const float* P_m_bhh   = WB + desc.off[17];
  const float* P_mr_Wih  = WB + desc.off[18];
  const float* P_mr_Whh  = WB + desc.off[19];
  const float* P_mr_bih  = WB + desc.off[20];
  const float* P_mr_bhh  = WB + desc.off[21];
  const float* P_W1      = WB + desc.off[22];
  const float* P_W2      = WB + desc.off[23];
  const float* P_pv      = WB + desc.off[24];
  const float* P_dWih    = WB + desc.off[25];
  const float* P_dWhh    = WB + desc.off[26];
  const float* P_dbih    = WB + desc.off[27];
  const float* P_dbhh    = WB + desc.off[28];

  size_t p = 16 + 1468512;
  // padded / restructured weights
  float* ctxWhhP = ws + p; p += 68400;    // [450][152]
  float* qWhhP   = ws + p; p += 68400;
  float* s2qCtx  = ws + p; p += 21696;    // [12][452] f4
  float* s2qQ    = ws + p; p += 21696;
  float* WcatF   = ws + p; p += 91200;    // [600][152]
  float* WcatR   = ws + p; p += 91200;
  float* s2qF    = ws + p; p += 24576;    // [12][512] f4
  float* s2qR    = ws + p; p += 24576;
  float* extFg   = ws + p; p += 13376;    // [38][88] f4
  float* extRg   = ws + p; p += 13376;

  float* ctx_gi = ws + p; p += 5760000;   // [B,T,450]; reused as enc later
  float* q_gi   = ws + p; p += 432000;    // [B,J,450]
  float* HpB    = ws + p; p += 1920000;   // [B,T,150]
  float* HqB    = ws + p; p += 144000;    // [B,J,150]
  float* whqB   = ws + p; p += 145920;    // [B,J,152]
  float* PfB    = ws + p; p += 433920;    // [B,J,452]
  float* PrB    = ws + p; p += 433920;
  float* pWpB   = ws + p; p += 1945600;   // [B,T,152]
  float* giXfB  = ws + p; p += 5785600;   // [B,T,452]
  float* giXrB  = ws + p; p += 5785600;
  float* HrB    = ws + p; p += 3849600;   // [B,401,300]
  float* encB   = ctx_gi;                 // [B,401,300]

  // 1) dtype sniff + weight conversion + restructured layouts
  sniff_kernel<<<1,256,0,stream>>>((const unsigned int*)d_in[2], flag);
  convert_weights_kernel<<<512,256,0,stream>>>(desc, WB, flag);
  padrows_kernel<<<(450*152+255)/256,256,0,stream>>>(P_ctx_Whh, ctxWhhP, 450,150,152);
  padrows_kernel<<<(450*152+255)/256,256,0,stream>>>(P_q_Whh,   qWhhP,   450,150,152);
  build_gsplit_kernel<<<(12*452*4+255)/256,256,0,stream>>>(ctxWhhP, s2qCtx);
  build_gsplit_kernel<<<(12*452*4+255)/256,256,0,stream>>>(qWhhP,   s2qQ);
  build_wcat_kernel<<<(600*152+255)/256,256,0,stream>>>(P_m_Whh,  P_Wr, WcatF);
  build_wcat_kernel<<<(600*152+255)/256,256,0,stream>>>(P_mr_Whh, P_Wr, WcatR);
  build_msplit_kernel<<<(24576+13376+255)/256,256,0,stream>>>(WcatF, s2qF, extFg);
  build_msplit_kernel<<<(24576+13376+255)/256,256,0,stream>>>(WcatR, s2qR, extRg);

  // 2) embedding + input projections for both encoders
  rowproj_kernel<<<1600,512,0,stream>>>(nullptr,(const int*)d_in[0], d_in[2], flag,
                                        P_ctx_Wih, P_ctx_bih, ctx_gi, 12800,450,150,1,150,0,450);
  rowproj_kernel<<<120,512,0,stream>>>(nullptr,(const int*)d_in[1], d_in[2], flag,
                                       P_q_Wih, P_q_bih, q_gi, 960,450,150,1,150,0,450);

  // 3) encoder scans
  gru_scan_kernel<<<64,512,0,stream>>>(ctx_gi, ctxWhhP, s2qCtx, P_ctx_bhh, HpB, 400,
                                       q_gi,   qWhhP,   s2qQ,   P_q_bhh,   HqB, 30);

  // 4) Hq/Hp-dependent precomputations (padded strides)
  rowproj_kernel<<<120,192,0,stream>>>(HqB,nullptr,nullptr,nullptr, P_Wq, nullptr,
                                       whqB, 960,150,150,0,150,0,152);
  rowproj_kernel<<<120,512,0,stream>>>(HqB,nullptr,nullptr,nullptr, P_m_Wih, nullptr,
                                       PfB, 960,450,150,1,300,150,452);
  rowproj_kernel<<<120,512,0,stream>>>(HqB,nullptr,nullptr,nullptr, P_mr_Wih, nullptr,
                                       PrB, 960,450,150,1,300,150,452);
  rowproj_kernel<<<1600,192,0,stream>>>(HpB,nullptr,nullptr,nullptr, P_Wp, P_gb,
                                        pWpB, 12800,150,150,0,150,0,152);
  rowproj_kernel<<<1600,512,0,stream>>>(HpB,nullptr,nullptr,nullptr, P_m_Wih, P_m_bih,
                                        giXfB, 12800,450,150,1,300,0,452);
  rowproj_kernel<<<1600,512,0,stream>>>(HpB,nullptr,nullptr,nullptr, P_mr_Wih, P_mr_bih,
                                        giXrB, 12800,450,150,1,300,0,452);

  // 5) match scans (fwd+bwd concurrent)
  zero_hr0_kernel<<<(NBATCH*300+511)/512,512,0,stream>>>(HrB);
  match_scan_kernel<<<dim3(NBATCH,2),512,0,stream>>>(pWpB, whqB, giXfB, giXrB,
                                                     PfB, PrB, WcatF, WcatR,
                                                     s2qF, s2qR, extFg, extRg,
                                                     P_m_bhh, P_mr_bhh, P_w, HrB);

  // 6) pointer decoder
  rowproj_kernel<<<1604,320,0,stream>>>(HrB,nullptr,nullptr,nullptr, P_W1, nullptr,
                                        encB, 12832,300,300,0,300,0,300);
  ptr_scan_kernel<<<32,512,0,stream>>>(encB, HrB, P_W2, P_pv,
                                       P_dWih, P_dWhh, P_dbih, P_dbhh, d_out, flag);
}